// Round 1
// baseline (831.888 us; speedup 1.0000x reference)
//
#include <hip/hip_runtime.h>

#define N_NODES 50000
#define E_EDGES 800000
#define D_DIM   128
#define LN_EPS  1e-5f

// ---------------- K0: zero the aggregation buffer (d_out) + denom ----------
__global__ void k0_init(float4* __restrict__ out4, float4* __restrict__ denom4,
                        int n_out4, int n_den4) {
    int i = blockIdx.x * blockDim.x + threadIdx.x;
    float4 z = make_float4(0.f, 0.f, 0.f, 0.f);
    if (i < n_out4) out4[i] = z;
    if (i < n_den4) denom4[i] = z;
}

// ---------------- K1a: transpose W_lin (128x128) -> Wt[d][o] ---------------
__global__ void k_transpose(const float* __restrict__ W, float* __restrict__ Wt) {
    int w = blockIdx.x * 256 + threadIdx.x;   // 64 blocks * 256 = 16384
    int d = w >> 7, o = w & 127;
    Wt[w] = W[o * 128 + d];                   // Wt[d][o] = W[o][d]
}

// ---------------- K1: h = x @ W^T, fused s_src/s_dst projections -----------
// block = 256 threads, 32 rows per block. 4x4 register tile per thread.
__global__ __launch_bounds__(256) void k_gemm(
        const float* __restrict__ x, const float* __restrict__ Wt,
        const float* __restrict__ Wa, float* __restrict__ h,
        float* __restrict__ ssrc, float* __restrict__ sdst) {
    __shared__ float xl[32 * 128];   // 16 KB, x rows (row-major, broadcast reads)
    __shared__ float wl[64 * 128];   // 32 KB, Wt chunk [dd][o] (consecutive b128 reads)
    const int tid = threadIdx.x;
    const int n0  = blockIdx.x * 32;

    // stage x rows (coalesced read, conflict-free write)
    #pragma unroll
    for (int i = 0; i < 4; ++i) {
        int idx = i * 256 + tid;              // float4 index into xl
        int row = idx >> 5, d4 = idx & 31;
        int n = n0 + row; if (n >= N_NODES) n = N_NODES - 1;
        ((float4*)xl)[idx] = ((const float4*)(x + (size_t)n * 128))[d4];
    }

    const int c = tid & 31;    // col group: cols 4c..4c+3
    const int r = tid >> 5;    // row group: rows 4r..4r+3
    float4 acc[4];
    #pragma unroll
    for (int j = 0; j < 4; ++j) acc[j] = make_float4(0.f, 0.f, 0.f, 0.f);

    for (int p = 0; p < 2; ++p) {            // two 64-deep K chunks (LDS budget)
        __syncthreads();
        #pragma unroll
        for (int i = 0; i < 8; ++i) {
            int idx = i * 256 + tid;
            ((float4*)wl)[idx] = ((const float4*)(Wt + (size_t)p * 64 * 128))[idx];
        }
        __syncthreads();
        #pragma unroll
        for (int d4 = 0; d4 < 16; ++d4) {
            float4 xv[4];
            #pragma unroll
            for (int j = 0; j < 4; ++j)
                xv[j] = *(const float4*)&xl[(4 * r + j) * 128 + p * 64 + 4 * d4];
            #pragma unroll
            for (int k = 0; k < 4; ++k) {
                float4 wv = *(const float4*)&wl[(4 * d4 + k) * 128 + 4 * c];
                #pragma unroll
                for (int j = 0; j < 4; ++j) {
                    float xs = (&xv[j].x)[k];
                    acc[j].x += xs * wv.x; acc[j].y += xs * wv.y;
                    acc[j].z += xs * wv.z; acc[j].w += xs * wv.w;
                }
            }
        }
    }

    // epilogue: store h, fused attention projections s_src/s_dst
    float as0 = Wa[4*c],       as1 = Wa[4*c+1],       as2 = Wa[4*c+2],       as3 = Wa[4*c+3];
    float ad0 = Wa[128+4*c],   ad1 = Wa[128+4*c+1],   ad2 = Wa[128+4*c+2],   ad3 = Wa[128+4*c+3];
    #pragma unroll
    for (int j = 0; j < 4; ++j) {
        int n = n0 + 4 * r + j;
        float ps = acc[j].x*as0 + acc[j].y*as1 + acc[j].z*as2 + acc[j].w*as3;
        float pd = acc[j].x*ad0 + acc[j].y*ad1 + acc[j].z*ad2 + acc[j].w*ad3;
        #pragma unroll
        for (int off = 16; off >= 1; off >>= 1) {   // reduce over the 32 col-lanes
            ps += __shfl_xor(ps, off);
            pd += __shfl_xor(pd, off);
        }
        if (n < N_NODES) {
            *(float4*)&h[(size_t)n * 128 + 4 * c] = acc[j];
            if (c == 0) { ssrc[n] = ps; sdst[n] = pd; }
        }
    }
}

// ---------------- K3: per-edge exp(score) * h[src] -> atomic agg -----------
// Softmax is shift-invariant => skip the segment-max pass entirely.
// One wave (64 lanes) per edge; lane l handles d = 2l, 2l+1.
__global__ void k_edge(const int* __restrict__ src, const int* __restrict__ dst,
                       const float* __restrict__ ssrc, const float* __restrict__ sdst,
                       const float* __restrict__ h, float* __restrict__ out,
                       float* __restrict__ denom) {
    int e    = blockIdx.x * 4 + (threadIdx.x >> 6);
    int lane = threadIdx.x & 63;
    int s  = src[e];
    int dv = dst[e];
    float sc = ssrc[s] + sdst[dv];
    sc = sc >= 0.f ? sc : 0.2f * sc;          // LeakyReLU(0.2)
    float ex = expf(sc);
    if (lane == 0) atomicAdd(&denom[dv], ex);
    float2 hv = *(const float2*)&h[(size_t)s * 128 + 2 * lane];
    size_t base = (size_t)dv * 128 + 2 * lane;
    atomicAdd(&out[base],     ex * hv.x);
    atomicAdd(&out[base + 1], ex * hv.y);
}

// ---------------- K4: out = LN(agg/denom + x) * scale + bias ---------------
// One wave per node, in-place on d_out.
__global__ void k_final(const float* __restrict__ x, const float* __restrict__ denom,
                        const float* __restrict__ scale, const float* __restrict__ bias,
                        float* __restrict__ out) {
    int n    = blockIdx.x * 4 + (threadIdx.x >> 6);
    int lane = threadIdx.x & 63;
    size_t base = (size_t)n * 128 + 2 * lane;
    float2 a  = *(float2*)&out[base];
    float den = denom[n];
    float sd  = den > 0.f ? den : 1.f;
    float2 xv = *(const float2*)&x[base];
    float r0 = a.x / sd + xv.x;
    float r1 = a.y / sd + xv.y;
    float sum = r0 + r1;
    #pragma unroll
    for (int off = 32; off >= 1; off >>= 1) sum += __shfl_xor(sum, off);
    float mu = sum * (1.f / 128.f);
    float d0 = r0 - mu, d1 = r1 - mu;
    float ss = d0 * d0 + d1 * d1;
    #pragma unroll
    for (int off = 32; off >= 1; off >>= 1) ss += __shfl_xor(ss, off);
    float inv = rsqrtf(ss * (1.f / 128.f) + LN_EPS);
    float o0 = d0 * inv * scale[2 * lane]     + bias[2 * lane];
    float o1 = d1 * inv * scale[2 * lane + 1] + bias[2 * lane + 1];
    *(float2*)&out[base] = make_float2(o0, o1);
}

extern "C" void kernel_launch(void* const* d_in, const int* in_sizes, int n_in,
                              void* d_out, int out_size, void* d_ws, size_t ws_size,
                              hipStream_t stream) {
    const float* x        = (const float*)d_in[0];
    const float* W_lin    = (const float*)d_in[1];
    const float* W_attn   = (const float*)d_in[2];
    const float* ln_scale = (const float*)d_in[3];
    const float* ln_bias  = (const float*)d_in[4];
    const int*   edge     = (const int*)d_in[5];
    float* out = (float*)d_out;

    char* ws = (char*)d_ws;
    float* h     = (float*)(ws);                 // 25,600,000 B
    float* Wt    = (float*)(ws + 25600000);      //     65,536 B
    float* denom = (float*)(ws + 25665536);      //    200,000 B
    float* ssrc  = (float*)(ws + 25865536);      //    200,000 B
    float* sdst  = (float*)(ws + 26065536);      //    200,000 B

    k0_init    <<<6250,   256, 0, stream>>>((float4*)out, (float4*)denom,
                                            N_NODES * D_DIM / 4, N_NODES / 4);
    k_transpose<<<64,     256, 0, stream>>>(W_lin, Wt);
    k_gemm     <<<1563,   256, 0, stream>>>(x, Wt, W_attn, h, ssrc, sdst);
    k_edge     <<<E_EDGES / 4, 256, 0, stream>>>(edge, edge + E_EDGES,
                                                 ssrc, sdst, h, out, denom);
    k_final    <<<N_NODES / 4, 256, 0, stream>>>(x, denom, ln_scale, ln_bias, out);
}

// Round 2
// 361.513 us; speedup vs baseline: 2.3011x; 2.3011x over previous
//
#include <hip/hip_runtime.h>

#define N_NODES 50000
#define E_EDGES 800000
#define D_DIM   128
#define LN_EPS  1e-5f

// ---------------- K0: zero the per-dst degree counters ---------------------
__global__ void k0_init(int* __restrict__ count) {
    int i = blockIdx.x * 256 + threadIdx.x;
    if (i < N_NODES) count[i] = 0;
}

// ---------------- K1a: transpose W_lin (128x128) -> Wt[d][o] ---------------
__global__ void k_transpose(const float* __restrict__ W, float* __restrict__ Wt) {
    int w = blockIdx.x * 256 + threadIdx.x;   // 64 blocks * 256 = 16384
    int d = w >> 7, o = w & 127;
    Wt[w] = W[o * 128 + d];                   // Wt[d][o] = W[o][d]
}

// ---------------- K1: h = x @ W^T, fused s_src/s_dst projections -----------
__global__ __launch_bounds__(256) void k_gemm(
        const float* __restrict__ x, const float* __restrict__ Wt,
        const float* __restrict__ Wa, float* __restrict__ h,
        float* __restrict__ ssrc, float* __restrict__ sdst) {
    __shared__ float xl[32 * 128];   // 16 KB
    __shared__ float wl[64 * 128];   // 32 KB
    const int tid = threadIdx.x;
    const int n0  = blockIdx.x * 32;

    #pragma unroll
    for (int i = 0; i < 4; ++i) {
        int idx = i * 256 + tid;
        int row = idx >> 5, d4 = idx & 31;
        int n = n0 + row; if (n >= N_NODES) n = N_NODES - 1;
        ((float4*)xl)[idx] = ((const float4*)(x + (size_t)n * 128))[d4];
    }

    const int c = tid & 31;
    const int r = tid >> 5;
    float4 acc[4];
    #pragma unroll
    for (int j = 0; j < 4; ++j) acc[j] = make_float4(0.f, 0.f, 0.f, 0.f);

    for (int p = 0; p < 2; ++p) {
        __syncthreads();
        #pragma unroll
        for (int i = 0; i < 8; ++i) {
            int idx = i * 256 + tid;
            ((float4*)wl)[idx] = ((const float4*)(Wt + (size_t)p * 64 * 128))[idx];
        }
        __syncthreads();
        #pragma unroll
        for (int d4 = 0; d4 < 16; ++d4) {
            float4 xv[4];
            #pragma unroll
            for (int j = 0; j < 4; ++j)
                xv[j] = *(const float4*)&xl[(4 * r + j) * 128 + p * 64 + 4 * d4];
            #pragma unroll
            for (int k = 0; k < 4; ++k) {
                float4 wv = *(const float4*)&wl[(4 * d4 + k) * 128 + 4 * c];
                #pragma unroll
                for (int j = 0; j < 4; ++j) {
                    float xs = (&xv[j].x)[k];
                    acc[j].x += xs * wv.x; acc[j].y += xs * wv.y;
                    acc[j].z += xs * wv.z; acc[j].w += xs * wv.w;
                }
            }
        }
    }

    float as0 = Wa[4*c],     as1 = Wa[4*c+1],     as2 = Wa[4*c+2],     as3 = Wa[4*c+3];
    float ad0 = Wa[128+4*c], ad1 = Wa[128+4*c+1], ad2 = Wa[128+4*c+2], ad3 = Wa[128+4*c+3];
    #pragma unroll
    for (int j = 0; j < 4; ++j) {
        int n = n0 + 4 * r + j;
        float ps = acc[j].x*as0 + acc[j].y*as1 + acc[j].z*as2 + acc[j].w*as3;
        float pd = acc[j].x*ad0 + acc[j].y*ad1 + acc[j].z*ad2 + acc[j].w*ad3;
        #pragma unroll
        for (int off = 16; off >= 1; off >>= 1) {
            ps += __shfl_xor(ps, off);
            pd += __shfl_xor(pd, off);
        }
        if (n < N_NODES) {
            *(float4*)&h[(size_t)n * 128 + 4 * c] = acc[j];
            if (c == 0) { ssrc[n] = ps; sdst[n] = pd; }
        }
    }
}

// ---------------- K2a: histogram of dst degrees ----------------------------
__global__ void k_hist(const int* __restrict__ dst, int* __restrict__ count) {
    int e = blockIdx.x * 256 + threadIdx.x;
    if (e < E_EDGES) atomicAdd(&count[dst[e]], 1);
}

// ---------------- K2b: exclusive scan -> rowptr; re-zero count (cursor) ----
__global__ __launch_bounds__(1024) void k_scan(int* __restrict__ count,
                                               int* __restrict__ rowptr) {
    __shared__ int tmp[1024];
    __shared__ int s_carry;
    const int tid = threadIdx.x;
    if (tid == 0) s_carry = 0;
    __syncthreads();
    for (int base = 0; base < N_NODES; base += 1024) {
        int i = base + tid;
        int v = (i < N_NODES) ? count[i] : 0;
        tmp[tid] = v;
        __syncthreads();
        for (int off = 1; off < 1024; off <<= 1) {
            int t = (tid >= off) ? tmp[tid - off] : 0;
            __syncthreads();
            tmp[tid] += t;
            __syncthreads();
        }
        int incl  = tmp[tid];
        int total = tmp[1023];
        if (i < N_NODES) { rowptr[i] = s_carry + incl - v; count[i] = 0; }
        __syncthreads();
        if (tid == 0) s_carry += total;
        __syncthreads();
    }
    if (tid == 0) rowptr[N_NODES] = s_carry;   // == E_EDGES
}

// ---------------- K2c: scatter edge src ids into CSR order -----------------
__global__ void k_scatter(const int* __restrict__ src, const int* __restrict__ dst,
                          const int* __restrict__ rowptr, int* __restrict__ cursor,
                          int* __restrict__ srcp) {
    int e = blockIdx.x * 256 + threadIdx.x;
    if (e >= E_EDGES) return;
    int dv = dst[e];
    int pos = rowptr[dv] + atomicAdd(&cursor[dv], 1);
    srcp[pos] = src[e];
}

// ---------------- K3: per-node gather-aggregate + fused residual+LN --------
// One wave per node; lane l handles d = 2l, 2l+1. No atomics anywhere.
__global__ __launch_bounds__(256) void k_gather(
        const int* __restrict__ rowptr, const int* __restrict__ srcp,
        const float* __restrict__ ssrc, const float* __restrict__ sdst,
        const float* __restrict__ h, const float* __restrict__ x,
        const float* __restrict__ scale, const float* __restrict__ bias,
        float* __restrict__ out) {
    int n    = blockIdx.x * 4 + (threadIdx.x >> 6);
    int lane = threadIdx.x & 63;
    int beg = rowptr[n], end = rowptr[n + 1];
    float sd_n = sdst[n];
    float a0 = 0.f, a1 = 0.f, b0 = 0.f, b1 = 0.f, den = 0.f;

    int i = beg;
    for (; i + 1 < end; i += 2) {               // 2-edge unroll for MLP
        int s0 = srcp[i], s1 = srcp[i + 1];
        float e0 = ssrc[s0], e1 = ssrc[s1];
        float2 h0 = *(const float2*)&h[(size_t)s0 * 128 + 2 * lane];
        float2 h1 = *(const float2*)&h[(size_t)s1 * 128 + 2 * lane];
        float sc0 = e0 + sd_n; sc0 = sc0 >= 0.f ? sc0 : 0.2f * sc0;
        float sc1 = e1 + sd_n; sc1 = sc1 >= 0.f ? sc1 : 0.2f * sc1;
        float ex0 = __expf(sc0), ex1 = __expf(sc1);
        den += ex0 + ex1;
        a0 += ex0 * h0.x; a1 += ex0 * h0.y;
        b0 += ex1 * h1.x; b1 += ex1 * h1.y;
    }
    if (i < end) {
        int s0 = srcp[i];
        float sc0 = ssrc[s0] + sd_n; sc0 = sc0 >= 0.f ? sc0 : 0.2f * sc0;
        float ex0 = __expf(sc0);
        den += ex0;
        float2 h0 = *(const float2*)&h[(size_t)s0 * 128 + 2 * lane];
        a0 += ex0 * h0.x; a1 += ex0 * h0.y;
    }
    a0 += b0; a1 += b1;

    float inv_d = 1.f / (den > 0.f ? den : 1.f);
    size_t base = (size_t)n * 128 + 2 * lane;
    float2 xv = *(const float2*)&x[base];
    float r0 = a0 * inv_d + xv.x;
    float r1 = a1 * inv_d + xv.y;

    float sum = r0 + r1;
    #pragma unroll
    for (int off = 32; off >= 1; off >>= 1) sum += __shfl_xor(sum, off);
    float mu = sum * (1.f / 128.f);
    float d0 = r0 - mu, d1 = r1 - mu;
    float ss = d0 * d0 + d1 * d1;
    #pragma unroll
    for (int off = 32; off >= 1; off >>= 1) ss += __shfl_xor(ss, off);
    float inv = rsqrtf(ss * (1.f / 128.f) + LN_EPS);
    float o0 = d0 * inv * scale[2 * lane]     + bias[2 * lane];
    float o1 = d1 * inv * scale[2 * lane + 1] + bias[2 * lane + 1];
    *(float2*)&out[base] = make_float2(o0, o1);
}

extern "C" void kernel_launch(void* const* d_in, const int* in_sizes, int n_in,
                              void* d_out, int out_size, void* d_ws, size_t ws_size,
                              hipStream_t stream) {
    const float* x        = (const float*)d_in[0];
    const float* W_lin    = (const float*)d_in[1];
    const float* W_attn   = (const float*)d_in[2];
    const float* ln_scale = (const float*)d_in[3];
    const float* ln_bias  = (const float*)d_in[4];
    const int*   edge     = (const int*)d_in[5];
    const int*   e_src    = edge;
    const int*   e_dst    = edge + E_EDGES;
    float* out = (float*)d_out;

    char* ws = (char*)d_ws;
    float* h      = (float*)(ws);                 // 25,600,000 B
    float* Wt     = (float*)(ws + 25600000);      //     65,536 B
    float* ssrc   = (float*)(ws + 25665536);      //    200,000 B
    float* sdst   = (float*)(ws + 25865536);      //    200,000 B
    int*   count  = (int*)  (ws + 26065536);      //    200,000 B (degree, then cursor)
    int*   rowptr = (int*)  (ws + 26265536);      //    200,004 B
    int*   srcp   = (int*)  (ws + 26465544);      //  3,200,000 B  (total ~29.7 MB)

    k0_init    <<<196,  256, 0, stream>>>(count);
    k_transpose<<<64,   256, 0, stream>>>(W_lin, Wt);
    k_gemm     <<<1563, 256, 0, stream>>>(x, Wt, W_attn, h, ssrc, sdst);
    k_hist     <<<3125, 256, 0, stream>>>(e_dst, count);
    k_scan     <<<1,   1024, 0, stream>>>(count, rowptr);
    k_scatter  <<<3125, 256, 0, stream>>>(e_src, e_dst, rowptr, count, srcp);
    k_gather   <<<12500,256, 0, stream>>>(rowptr, srcp, ssrc, sdst, h, x,
                                          ln_scale, ln_bias, out);
}

// Round 3
// 266.623 us; speedup vs baseline: 3.1201x; 1.3559x over previous
//
#include <hip/hip_runtime.h>

#define N_NODES 50000
#define E_EDGES 800000
#define D_DIM   128
#define LN_EPS  1e-5f
#define SCAN_BLOCKS 196   // ceil(50000/256)

// ---------------- K0: zero the per-dst degree counters ---------------------
__global__ void k0_init(int* __restrict__ count) {
    int i = blockIdx.x * 256 + threadIdx.x;
    if (i < N_NODES) count[i] = 0;
}

// ---------------- K1a: transpose W_lin (128x128) -> Wt[d][o] ---------------
__global__ void k_transpose(const float* __restrict__ W, float* __restrict__ Wt) {
    int w = blockIdx.x * 256 + threadIdx.x;   // 64 blocks * 256 = 16384
    int d = w >> 7, o = w & 127;
    Wt[w] = W[o * 128 + d];                   // Wt[d][o] = W[o][d]
}

// ---------------- K1: h = x @ W^T, fused s_src/s_dst projections -----------
__global__ __launch_bounds__(256) void k_gemm(
        const float* __restrict__ x, const float* __restrict__ Wt,
        const float* __restrict__ Wa, float* __restrict__ h,
        float* __restrict__ ssrc, float* __restrict__ sdst) {
    __shared__ float xl[32 * 128];   // 16 KB
    __shared__ float wl[64 * 128];   // 32 KB
    const int tid = threadIdx.x;
    const int n0  = blockIdx.x * 32;

    #pragma unroll
    for (int i = 0; i < 4; ++i) {
        int idx = i * 256 + tid;
        int row = idx >> 5, d4 = idx & 31;
        int n = n0 + row; if (n >= N_NODES) n = N_NODES - 1;
        ((float4*)xl)[idx] = ((const float4*)(x + (size_t)n * 128))[d4];
    }

    const int c = tid & 31;
    const int r = tid >> 5;
    float4 acc[4];
    #pragma unroll
    for (int j = 0; j < 4; ++j) acc[j] = make_float4(0.f, 0.f, 0.f, 0.f);

    for (int p = 0; p < 2; ++p) {
        __syncthreads();
        #pragma unroll
        for (int i = 0; i < 8; ++i) {
            int idx = i * 256 + tid;
            ((float4*)wl)[idx] = ((const float4*)(Wt + (size_t)p * 64 * 128))[idx];
        }
        __syncthreads();
        #pragma unroll
        for (int d4 = 0; d4 < 16; ++d4) {
            float4 xv[4];
            #pragma unroll
            for (int j = 0; j < 4; ++j)
                xv[j] = *(const float4*)&xl[(4 * r + j) * 128 + p * 64 + 4 * d4];
            #pragma unroll
            for (int k = 0; k < 4; ++k) {
                float4 wv = *(const float4*)&wl[(4 * d4 + k) * 128 + 4 * c];
                #pragma unroll
                for (int j = 0; j < 4; ++j) {
                    float xs = (&xv[j].x)[k];
                    acc[j].x += xs * wv.x; acc[j].y += xs * wv.y;
                    acc[j].z += xs * wv.z; acc[j].w += xs * wv.w;
                }
            }
        }
    }

    float as0 = Wa[4*c],     as1 = Wa[4*c+1],     as2 = Wa[4*c+2],     as3 = Wa[4*c+3];
    float ad0 = Wa[128+4*c], ad1 = Wa[128+4*c+1], ad2 = Wa[128+4*c+2], ad3 = Wa[128+4*c+3];
    #pragma unroll
    for (int j = 0; j < 4; ++j) {
        int n = n0 + 4 * r + j;
        float ps = acc[j].x*as0 + acc[j].y*as1 + acc[j].z*as2 + acc[j].w*as3;
        float pd = acc[j].x*ad0 + acc[j].y*ad1 + acc[j].z*ad2 + acc[j].w*ad3;
        #pragma unroll
        for (int off = 16; off >= 1; off >>= 1) {
            ps += __shfl_xor(ps, off);
            pd += __shfl_xor(pd, off);
        }
        if (n < N_NODES) {
            *(float4*)&h[(size_t)n * 128 + 4 * c] = acc[j];
            if (c == 0) { ssrc[n] = ps; sdst[n] = pd; }
        }
    }
}

// ---------------- K2a: histogram of dst degrees ----------------------------
__global__ void k_hist(const int* __restrict__ dst, int* __restrict__ count) {
    int e = blockIdx.x * 256 + threadIdx.x;
    if (e < E_EDGES) atomicAdd(&count[dst[e]], 1);
}

// ---------------- K2b.1: per-block exclusive scan (256 elems/block) --------
// rowptr[i] = local exclusive prefix; bsum[b] = block total.
__global__ __launch_bounds__(256) void k_scan1(const int* __restrict__ count,
                                               int* __restrict__ rowptr,
                                               int* __restrict__ bsum) {
    __shared__ int wsum[4];
    const int tid  = threadIdx.x;
    const int lane = tid & 63, w = tid >> 6;
    int i = blockIdx.x * 256 + tid;
    int v = (i < N_NODES) ? count[i] : 0;
    int sc = v;
    #pragma unroll
    for (int off = 1; off < 64; off <<= 1) {
        int t = __shfl_up(sc, off);
        if (lane >= off) sc += t;
    }
    if (lane == 63) wsum[w] = sc;
    __syncthreads();
    if (tid == 0) {
        int s0 = wsum[0], s1 = wsum[1], s2 = wsum[2], s3 = wsum[3];
        wsum[0] = 0; wsum[1] = s0; wsum[2] = s0 + s1; wsum[3] = s0 + s1 + s2;
        bsum[blockIdx.x] = s0 + s1 + s2 + s3;
    }
    __syncthreads();
    if (i < N_NODES) rowptr[i] = sc - v + wsum[w];
}

// ---------------- K2b.2: exclusive scan of the 196 block sums --------------
__global__ __launch_bounds__(256) void k_scan2(int* __restrict__ bsum) {
    __shared__ int wsum[4];
    const int tid  = threadIdx.x;
    const int lane = tid & 63, w = tid >> 6;
    int v = (tid < SCAN_BLOCKS) ? bsum[tid] : 0;
    int sc = v;
    #pragma unroll
    for (int off = 1; off < 64; off <<= 1) {
        int t = __shfl_up(sc, off);
        if (lane >= off) sc += t;
    }
    if (lane == 63) wsum[w] = sc;
    __syncthreads();
    if (tid == 0) {
        int s0 = wsum[0], s1 = wsum[1], s2 = wsum[2];
        wsum[3] = s0 + s1 + s2; wsum[2] = s0 + s1; wsum[1] = s0; wsum[0] = 0;
    }
    __syncthreads();
    if (tid < SCAN_BLOCKS) bsum[tid] = sc - v + wsum[w];
}

// ---------------- K2b.3: add block offsets; zero cursor; cap rowptr --------
__global__ void k_scan3(int* __restrict__ rowptr, const int* __restrict__ bsum,
                        int* __restrict__ count) {
    int i = blockIdx.x * 256 + threadIdx.x;
    if (i < N_NODES) {
        rowptr[i] += bsum[i >> 8];
        count[i] = 0;
    }
    if (i == 0) rowptr[N_NODES] = E_EDGES;
}

// ---------------- K2c: scatter edge src ids into CSR order -----------------
__global__ void k_scatter(const int* __restrict__ src, const int* __restrict__ dst,
                          const int* __restrict__ rowptr, int* __restrict__ cursor,
                          int* __restrict__ srcp) {
    int e = blockIdx.x * 256 + threadIdx.x;
    if (e >= E_EDGES) return;
    int dv = dst[e];
    int pos = rowptr[dv] + atomicAdd(&cursor[dv], 1);
    srcp[pos] = src[e];
}

// ---------------- K3: per-node gather-aggregate + fused residual+LN --------
// One wave per node; lane l handles d = 2l, 2l+1. No atomics anywhere.
__global__ __launch_bounds__(256) void k_gather(
        const int* __restrict__ rowptr, const int* __restrict__ srcp,
        const float* __restrict__ ssrc, const float* __restrict__ sdst,
        const float* __restrict__ h, const float* __restrict__ x,
        const float* __restrict__ scale, const float* __restrict__ bias,
        float* __restrict__ out) {
    int n    = blockIdx.x * 4 + (threadIdx.x >> 6);
    int lane = threadIdx.x & 63;
    int beg = rowptr[n], end = rowptr[n + 1];
    float sd_n = sdst[n];
    float a0 = 0.f, a1 = 0.f, b0 = 0.f, b1 = 0.f, den = 0.f;

    int i = beg;
    for (; i + 1 < end; i += 2) {               // 2-edge unroll for MLP
        int s0 = srcp[i], s1 = srcp[i + 1];
        float e0 = ssrc[s0], e1 = ssrc[s1];
        float2 h0 = *(const float2*)&h[(size_t)s0 * 128 + 2 * lane];
        float2 h1 = *(const float2*)&h[(size_t)s1 * 128 + 2 * lane];
        float sc0 = e0 + sd_n; sc0 = sc0 >= 0.f ? sc0 : 0.2f * sc0;
        float sc1 = e1 + sd_n; sc1 = sc1 >= 0.f ? sc1 : 0.2f * sc1;
        float ex0 = __expf(sc0), ex1 = __expf(sc1);
        den += ex0 + ex1;
        a0 += ex0 * h0.x; a1 += ex0 * h0.y;
        b0 += ex1 * h1.x; b1 += ex1 * h1.y;
    }
    if (i < end) {
        int s0 = srcp[i];
        float sc0 = ssrc[s0] + sd_n; sc0 = sc0 >= 0.f ? sc0 : 0.2f * sc0;
        float ex0 = __expf(sc0);
        den += ex0;
        float2 h0 = *(const float2*)&h[(size_t)s0 * 128 + 2 * lane];
        a0 += ex0 * h0.x; a1 += ex0 * h0.y;
    }
    a0 += b0; a1 += b1;

    float inv_d = 1.f / (den > 0.f ? den : 1.f);
    size_t base = (size_t)n * 128 + 2 * lane;
    float2 xv = *(const float2*)&x[base];
    float r0 = a0 * inv_d + xv.x;
    float r1 = a1 * inv_d + xv.y;

    float sum = r0 + r1;
    #pragma unroll
    for (int off = 32; off >= 1; off >>= 1) sum += __shfl_xor(sum, off);
    float mu = sum * (1.f / 128.f);
    float d0 = r0 - mu, d1 = r1 - mu;
    float ss = d0 * d0 + d1 * d1;
    #pragma unroll
    for (int off = 32; off >= 1; off >>= 1) ss += __shfl_xor(ss, off);
    float inv = rsqrtf(ss * (1.f / 128.f) + LN_EPS);
    float o0 = d0 * inv * scale[2 * lane]     + bias[2 * lane];
    float o1 = d1 * inv * scale[2 * lane + 1] + bias[2 * lane + 1];
    *(float2*)&out[base] = make_float2(o0, o1);
}

extern "C" void kernel_launch(void* const* d_in, const int* in_sizes, int n_in,
                              void* d_out, int out_size, void* d_ws, size_t ws_size,
                              hipStream_t stream) {
    const float* x        = (const float*)d_in[0];
    const float* W_lin    = (const float*)d_in[1];
    const float* W_attn   = (const float*)d_in[2];
    const float* ln_scale = (const float*)d_in[3];
    const float* ln_bias  = (const float*)d_in[4];
    const int*   edge     = (const int*)d_in[5];
    const int*   e_src    = edge;
    const int*   e_dst    = edge + E_EDGES;
    float* out = (float*)d_out;

    char* ws = (char*)d_ws;
    float* h      = (float*)(ws);                 // 25,600,000 B
    float* Wt     = (float*)(ws + 25600000);      //     65,536 B
    float* ssrc   = (float*)(ws + 25665536);      //    200,000 B
    float* sdst   = (float*)(ws + 25865536);      //    200,000 B
    int*   count  = (int*)  (ws + 26065536);      //    200,000 B (degree, then cursor)
    int*   rowptr = (int*)  (ws + 26265536);      //    200,004 B
    int*   bsum   = (int*)  (ws + 26465544);      //        784 B
    int*   srcp   = (int*)  (ws + 26466328);      //  3,200,000 B  (total ~29.7 MB)

    k0_init    <<<SCAN_BLOCKS, 256, 0, stream>>>(count);
    k_transpose<<<64,   256, 0, stream>>>(W_lin, Wt);
    k_gemm     <<<1563, 256, 0, stream>>>(x, Wt, W_attn, h, ssrc, sdst);
    k_hist     <<<3125, 256, 0, stream>>>(e_dst, count);
    k_scan1    <<<SCAN_BLOCKS, 256, 0, stream>>>(count, rowptr, bsum);
    k_scan2    <<<1,    256, 0, stream>>>(bsum);
    k_scan3    <<<SCAN_BLOCKS, 256, 0, stream>>>(rowptr, bsum, count);
    k_scatter  <<<3125, 256, 0, stream>>>(e_src, e_dst, rowptr, count, srcp);
    k_gather   <<<12500,256, 0, stream>>>(rowptr, srcp, ssrc, sdst, h, x,
                                          ln_scale, ln_bias, out);
}

// Round 5
// 258.879 us; speedup vs baseline: 3.2134x; 1.0299x over previous
//
#include <hip/hip_runtime.h>

#define N_NODES 50000
#define E_EDGES 800000
#define D_DIM   128
#define LN_EPS  1e-5f
#define SCAN_BLOCKS 196   // ceil(50000/256)

// fp32 -> bf16 (round to nearest even), stored as raw ushort
__device__ inline unsigned short f2b(float f) {
    unsigned int u = __float_as_uint(f);
    unsigned int r = u + 0x7FFFu + ((u >> 16) & 1u);
    return (unsigned short)(r >> 16);
}

// ---------------- K_prep: zero dst-degree counters + transpose W_lin -------
__global__ void k_prep(const float* __restrict__ W, float* __restrict__ Wt,
                       int* __restrict__ count) {
    int i = blockIdx.x * 256 + threadIdx.x;
    if (i < N_NODES) count[i] = 0;
    if (i < 16384) {                          // Wt[d][o] = W[o][d]
        int d = i >> 7, o = i & 127;
        Wt[i] = W[o * 128 + d];
    }
}

// ---------------- K1: h = x @ W^T (fp32, proven), bf16 h out, fused scores -
__global__ __launch_bounds__(256) void k_gemm(
        const float* __restrict__ x, const float* __restrict__ Wt,
        const float* __restrict__ Wa, unsigned short* __restrict__ hb,
        float* __restrict__ ssrc, float* __restrict__ sdst) {
    __shared__ float xl[32 * 128];   // 16 KB
    __shared__ float wl[64 * 128];   // 32 KB
    const int tid = threadIdx.x;
    const int n0  = blockIdx.x * 32;

    #pragma unroll
    for (int i = 0; i < 4; ++i) {
        int idx = i * 256 + tid;
        int row = idx >> 5, d4 = idx & 31;
        int n = n0 + row; if (n >= N_NODES) n = N_NODES - 1;
        ((float4*)xl)[idx] = ((const float4*)(x + (size_t)n * 128))[d4];
    }

    const int c = tid & 31;
    const int r = tid >> 5;
    float4 acc[4];
    #pragma unroll
    for (int j = 0; j < 4; ++j) acc[j] = make_float4(0.f, 0.f, 0.f, 0.f);

    for (int p = 0; p < 2; ++p) {
        __syncthreads();
        #pragma unroll
        for (int i = 0; i < 8; ++i) {
            int idx = i * 256 + tid;
            ((float4*)wl)[idx] = ((const float4*)(Wt + (size_t)p * 64 * 128))[idx];
        }
        __syncthreads();
        #pragma unroll
        for (int d4 = 0; d4 < 16; ++d4) {
            float4 xv[4];
            #pragma unroll
            for (int j = 0; j < 4; ++j)
                xv[j] = *(const float4*)&xl[(4 * r + j) * 128 + p * 64 + 4 * d4];
            #pragma unroll
            for (int k = 0; k < 4; ++k) {
                float4 wv = *(const float4*)&wl[(4 * d4 + k) * 128 + 4 * c];
                #pragma unroll
                for (int j = 0; j < 4; ++j) {
                    float xs = (&xv[j].x)[k];
                    acc[j].x += xs * wv.x; acc[j].y += xs * wv.y;
                    acc[j].z += xs * wv.z; acc[j].w += xs * wv.w;
                }
            }
        }
    }

    float as0 = Wa[4*c],     as1 = Wa[4*c+1],     as2 = Wa[4*c+2],     as3 = Wa[4*c+3];
    float ad0 = Wa[128+4*c], ad1 = Wa[128+4*c+1], ad2 = Wa[128+4*c+2], ad3 = Wa[128+4*c+3];
    #pragma unroll
    for (int j = 0; j < 4; ++j) {
        int n = n0 + 4 * r + j;
        float ps = acc[j].x*as0 + acc[j].y*as1 + acc[j].z*as2 + acc[j].w*as3;
        float pd = acc[j].x*ad0 + acc[j].y*ad1 + acc[j].z*ad2 + acc[j].w*ad3;
        #pragma unroll
        for (int off = 16; off >= 1; off >>= 1) {
            ps += __shfl_xor(ps, off);
            pd += __shfl_xor(pd, off);
        }
        if (n < N_NODES) {
            ushort4 b4;
            b4.x = f2b(acc[j].x); b4.y = f2b(acc[j].y);
            b4.z = f2b(acc[j].z); b4.w = f2b(acc[j].w);
            *(ushort4*)&hb[(size_t)n * 128 + 4 * c] = b4;
            if (c == 0) { ssrc[n] = ps; sdst[n] = pd; }
        }
    }
}

// ---------------- K2a: histogram of dst degrees ----------------------------
__global__ void k_hist(const int* __restrict__ dst, int* __restrict__ count) {
    int e = blockIdx.x * 256 + threadIdx.x;
    if (e < E_EDGES) atomicAdd(&count[dst[e]], 1);
}

// ---------------- K2b.1: per-block exclusive scan (256 elems/block) --------
__global__ __launch_bounds__(256) void k_scan1(const int* __restrict__ count,
                                               int* __restrict__ rowptr,
                                               int* __restrict__ bsum) {
    __shared__ int wsum[4];
    const int tid  = threadIdx.x;
    const int lane = tid & 63, w = tid >> 6;
    int i = blockIdx.x * 256 + tid;
    int v = (i < N_NODES) ? count[i] : 0;
    int sc = v;
    #pragma unroll
    for (int off = 1; off < 64; off <<= 1) {
        int t = __shfl_up(sc, off);
        if (lane >= off) sc += t;
    }
    if (lane == 63) wsum[w] = sc;
    __syncthreads();
    if (tid == 0) {
        int s0 = wsum[0], s1 = wsum[1], s2 = wsum[2], s3 = wsum[3];
        wsum[0] = 0; wsum[1] = s0; wsum[2] = s0 + s1; wsum[3] = s0 + s1 + s2;
        bsum[blockIdx.x] = s0 + s1 + s2 + s3;
    }
    __syncthreads();
    if (i < N_NODES) rowptr[i] = sc - v + wsum[w];
}

// ---------------- K2b.2: exclusive scan of the 196 block sums --------------
__global__ __launch_bounds__(256) void k_scan2(int* __restrict__ bsum) {
    __shared__ int wsum[4];
    const int tid  = threadIdx.x;
    const int lane = tid & 63, w = tid >> 6;
    int v = (tid < SCAN_BLOCKS) ? bsum[tid] : 0;
    int sc = v;
    #pragma unroll
    for (int off = 1; off < 64; off <<= 1) {
        int t = __shfl_up(sc, off);
        if (lane >= off) sc += t;
    }
    if (lane == 63) wsum[w] = sc;
    __syncthreads();
    if (tid == 0) {
        int s0 = wsum[0], s1 = wsum[1], s2 = wsum[2];
        wsum[3] = s0 + s1 + s2; wsum[2] = s0 + s1; wsum[1] = s0; wsum[0] = 0;
    }
    __syncthreads();
    if (tid < SCAN_BLOCKS) bsum[tid] = sc - v + wsum[w];
}

// ---------------- K2b.3: add block offsets; zero cursor; cap rowptr --------
__global__ void k_scan3(int* __restrict__ rowptr, const int* __restrict__ bsum,
                        int* __restrict__ count) {
    int i = blockIdx.x * 256 + threadIdx.x;
    if (i < N_NODES) {
        rowptr[i] += bsum[i >> 8];
        count[i] = 0;
    }
    if (i == 0) rowptr[N_NODES] = E_EDGES;
}

// ---------------- K2c: scatter edge src ids into CSR order -----------------
__global__ void k_scatter(const int* __restrict__ src, const int* __restrict__ dst,
                          const int* __restrict__ rowptr, int* __restrict__ cursor,
                          int* __restrict__ srcp) {
    int e = blockIdx.x * 256 + threadIdx.x;
    if (e >= E_EDGES) return;
    int dv = dst[e];
    int pos = rowptr[dv] + atomicAdd(&cursor[dv], 1);
    srcp[pos] = src[e];
}

// ---------------- K3: per-node gather-aggregate + fused residual+LN --------
// One wave per node; lane l handles dims 2l, 2l+1 (bf16 h: one uint per lane).
__global__ __launch_bounds__(256) void k_gather(
        const int* __restrict__ rowptr, const int* __restrict__ srcp,
        const float* __restrict__ ssrc, const float* __restrict__ sdst,
        const unsigned short* __restrict__ hb, const float* __restrict__ x,
        const float* __restrict__ scale, const float* __restrict__ bias,
        float* __restrict__ out) {
    int n    = blockIdx.x * 4 + (threadIdx.x >> 6);
    int lane = threadIdx.x & 63;
    int beg = rowptr[n], end = rowptr[n + 1];
    float sd_n = sdst[n];
    float a0 = 0.f, a1 = 0.f, b0 = 0.f, b1 = 0.f, den = 0.f;

    int i = beg;
    for (; i + 1 < end; i += 2) {
        int s0 = srcp[i], s1 = srcp[i + 1];
        float e0 = ssrc[s0], e1 = ssrc[s1];
        unsigned int u0 = *(const unsigned int*)&hb[(size_t)s0 * 128 + 2 * lane];
        unsigned int u1 = *(const unsigned int*)&hb[(size_t)s1 * 128 + 2 * lane];
        float sc0 = e0 + sd_n; sc0 = sc0 >= 0.f ? sc0 : 0.2f * sc0;
        float sc1 = e1 + sd_n; sc1 = sc1 >= 0.f ? sc1 : 0.2f * sc1;
        float ex0 = __expf(sc0), ex1 = __expf(sc1);
        den += ex0 + ex1;
        a0 += ex0 * __uint_as_float(u0 << 16);
        a1 += ex0 * __uint_as_float(u0 & 0xFFFF0000u);
        b0 += ex1 * __uint_as_float(u1 << 16);
        b1 += ex1 * __uint_as_float(u1 & 0xFFFF0000u);
    }
    if (i < end) {
        int s0 = srcp[i];
        float sc0 = ssrc[s0] + sd_n; sc0 = sc0 >= 0.f ? sc0 : 0.2f * sc0;
        float ex0 = __expf(sc0);
        den += ex0;
        unsigned int u0 = *(const unsigned int*)&hb[(size_t)s0 * 128 + 2 * lane];
        a0 += ex0 * __uint_as_float(u0 << 16);
        a1 += ex0 * __uint_as_float(u0 & 0xFFFF0000u);
    }
    a0 += b0; a1 += b1;

    float inv_d = 1.f / (den > 0.f ? den : 1.f);
    size_t base = (size_t)n * 128 + 2 * lane;
    float2 xv = *(const float2*)&x[base];
    float r0 = a0 * inv_d + xv.x;
    float r1 = a1 * inv_d + xv.y;

    float sum = r0 + r1;
    #pragma unroll
    for (int off = 32; off >= 1; off >>= 1) sum += __shfl_xor(sum, off);
    float mu = sum * (1.f / 128.f);
    float d0 = r0 - mu, d1 = r1 - mu;
    float ss = d0 * d0 + d1 * d1;
    #pragma unroll
    for (int off = 32; off >= 1; off >>= 1) ss += __shfl_xor(ss, off);
    float inv = rsqrtf(ss * (1.f / 128.f) + LN_EPS);
    float o0 = d0 * inv * scale[2 * lane]     + bias[2 * lane];
    float o1 = d1 * inv * scale[2 * lane + 1] + bias[2 * lane + 1];
    *(float2*)&out[base] = make_float2(o0, o1);
}

extern "C" void kernel_launch(void* const* d_in, const int* in_sizes, int n_in,
                              void* d_out, int out_size, void* d_ws, size_t ws_size,
                              hipStream_t stream) {
    const float* x        = (const float*)d_in[0];
    const float* W_lin    = (const float*)d_in[1];
    const float* W_attn   = (const float*)d_in[2];
    const float* ln_scale = (const float*)d_in[3];
    const float* ln_bias  = (const float*)d_in[4];
    const int*   edge     = (const int*)d_in[5];
    const int*   e_src    = edge;
    const int*   e_dst    = edge + E_EDGES;
    float* out = (float*)d_out;

    char* ws = (char*)d_ws;
    unsigned short* hb = (unsigned short*)(ws);   // 12,800,000 B
    float* Wt     = (float*)(ws + 12800000);      //     65,536 B
    float* ssrc   = (float*)(ws + 12865536);      //    200,000 B
    float* sdst   = (float*)(ws + 13065536);      //    200,000 B
    int*   count  = (int*)  (ws + 13265536);      //    200,000 B (degree, then cursor)
    int*   rowptr = (int*)  (ws + 13465536);      //    200,008 B (padded)
    int*   bsum   = (int*)  (ws + 13665544);      //        792 B (padded)
    int*   srcp   = (int*)  (ws + 13666336);      //  3,200,000 B  (~16.9 MB)

    k_prep   <<<SCAN_BLOCKS, 256, 0, stream>>>(W_lin, Wt, count);
    k_gemm   <<<1563, 256, 0, stream>>>(x, Wt, W_attn, hb, ssrc, sdst);
    k_hist   <<<3125, 256, 0, stream>>>(e_dst, count);
    k_scan1  <<<SCAN_BLOCKS, 256, 0, stream>>>(count, rowptr, bsum);
    k_scan2  <<<1,    256, 0, stream>>>(bsum);
    k_scan3  <<<SCAN_BLOCKS, 256, 0, stream>>>(rowptr, bsum, count);
    k_scatter<<<3125, 256, 0, stream>>>(e_src, e_dst, rowptr, count, srcp);
    k_gather <<<12500,256, 0, stream>>>(rowptr, srcp, ssrc, sdst, hb, x,
                                        ln_scale, ln_bias, out);
}

// Round 6
// 234.772 us; speedup vs baseline: 3.5434x; 1.1027x over previous
//
#include <hip/hip_runtime.h>

#define N_NODES 50000
#define E_EDGES 800000
#define D_DIM   128
#define LN_EPS  1e-5f
#define SCAN_BLOCKS 196   // ceil(50000/256)
#define HIST_BLOCKS 3125  // 800000/256 exactly
#define GEMM_BLOCKS 1563  // ceil(50000/32)

// fp32 -> bf16 (round to nearest even), stored as raw ushort
__device__ inline unsigned short f2b(float f) {
    unsigned int u = __float_as_uint(f);
    unsigned int r = u + 0x7FFFu + ((u >> 16) & 1u);
    return (unsigned short)(r >> 16);
}

// ---------------- K_prep: zero count+cursor, transpose W_lin ---------------
__global__ void k_prep(const float* __restrict__ W, float* __restrict__ Wt,
                       int* __restrict__ count, int* __restrict__ cursor) {
    int i = blockIdx.x * 256 + threadIdx.x;
    if (i < N_NODES) { count[i] = 0; cursor[i] = 0; }
    if (i < 16384) {                          // Wt[d][o] = W[o][d]
        int d = i >> 7, o = i & 127;
        Wt[i] = W[o * 128 + d];
    }
}

// ---------------- K1: fused [hist blocks] + [gemm blocks] ------------------
// blocks [0, HIST_BLOCKS): dst-degree histogram (starts immediately, hides
// under the gemm). blocks [HIST_BLOCKS, +GEMM_BLOCKS): fp32 GEMM (proven),
// bf16 h out, fused s_src/s_dst projections.
__global__ __launch_bounds__(256) void k_gemm_hist(
        const float* __restrict__ x, const float* __restrict__ Wt,
        const float* __restrict__ Wa, const int* __restrict__ dst,
        int* __restrict__ count, unsigned short* __restrict__ hb,
        float* __restrict__ ssrc, float* __restrict__ sdst) {
    __shared__ float xl[32 * 128];   // 16 KB
    __shared__ float wl[64 * 128];   // 32 KB
    const int tid = threadIdx.x;

    if (blockIdx.x < HIST_BLOCKS) {
        int e = blockIdx.x * 256 + tid;       // exactly 800000 threads
        atomicAdd(&count[dst[e]], 1);
        return;
    }

    const int n0 = (blockIdx.x - HIST_BLOCKS) * 32;

    #pragma unroll
    for (int i = 0; i < 4; ++i) {
        int idx = i * 256 + tid;
        int row = idx >> 5, d4 = idx & 31;
        int n = n0 + row; if (n >= N_NODES) n = N_NODES - 1;
        ((float4*)xl)[idx] = ((const float4*)(x + (size_t)n * 128))[d4];
    }

    const int c = tid & 31;
    const int r = tid >> 5;
    float4 acc[4];
    #pragma unroll
    for (int j = 0; j < 4; ++j) acc[j] = make_float4(0.f, 0.f, 0.f, 0.f);

    for (int p = 0; p < 2; ++p) {
        __syncthreads();
        #pragma unroll
        for (int i = 0; i < 8; ++i) {
            int idx = i * 256 + tid;
            ((float4*)wl)[idx] = ((const float4*)(Wt + (size_t)p * 64 * 128))[idx];
        }
        __syncthreads();
        #pragma unroll
        for (int d4 = 0; d4 < 16; ++d4) {
            float4 xv[4];
            #pragma unroll
            for (int j = 0; j < 4; ++j)
                xv[j] = *(const float4*)&xl[(4 * r + j) * 128 + p * 64 + 4 * d4];
            #pragma unroll
            for (int k = 0; k < 4; ++k) {
                float4 wv = *(const float4*)&wl[(4 * d4 + k) * 128 + 4 * c];
                #pragma unroll
                for (int j = 0; j < 4; ++j) {
                    float xs = (&xv[j].x)[k];
                    acc[j].x += xs * wv.x; acc[j].y += xs * wv.y;
                    acc[j].z += xs * wv.z; acc[j].w += xs * wv.w;
                }
            }
        }
    }

    float as0 = Wa[4*c],     as1 = Wa[4*c+1],     as2 = Wa[4*c+2],     as3 = Wa[4*c+3];
    float ad0 = Wa[128+4*c], ad1 = Wa[128+4*c+1], ad2 = Wa[128+4*c+2], ad3 = Wa[128+4*c+3];
    #pragma unroll
    for (int j = 0; j < 4; ++j) {
        int n = n0 + 4 * r + j;
        float ps = acc[j].x*as0 + acc[j].y*as1 + acc[j].z*as2 + acc[j].w*as3;
        float pd = acc[j].x*ad0 + acc[j].y*ad1 + acc[j].z*ad2 + acc[j].w*ad3;
        #pragma unroll
        for (int off = 16; off >= 1; off >>= 1) {
            ps += __shfl_xor(ps, off);
            pd += __shfl_xor(pd, off);
        }
        if (n < N_NODES) {
            ushort4 b4;
            b4.x = f2b(acc[j].x); b4.y = f2b(acc[j].y);
            b4.z = f2b(acc[j].z); b4.w = f2b(acc[j].w);
            *(ushort4*)&hb[(size_t)n * 128 + 4 * c] = b4;
            if (c == 0) { ssrc[n] = ps; sdst[n] = pd; }
        }
    }
}

// ---------------- K2b.1: per-block exclusive scan (256 elems/block) --------
__global__ __launch_bounds__(256) void k_scan1(const int* __restrict__ count,
                                               int* __restrict__ rowptr,
                                               int* __restrict__ bsum) {
    __shared__ int wsum[4];
    const int tid  = threadIdx.x;
    const int lane = tid & 63, w = tid >> 6;
    int i = blockIdx.x * 256 + tid;
    int v = (i < N_NODES) ? count[i] : 0;
    int sc = v;
    #pragma unroll
    for (int off = 1; off < 64; off <<= 1) {
        int t = __shfl_up(sc, off);
        if (lane >= off) sc += t;
    }
    if (lane == 63) wsum[w] = sc;
    __syncthreads();
    if (tid == 0) {
        int s0 = wsum[0], s1 = wsum[1], s2 = wsum[2], s3 = wsum[3];
        wsum[0] = 0; wsum[1] = s0; wsum[2] = s0 + s1; wsum[3] = s0 + s1 + s2;
        bsum[blockIdx.x] = s0 + s1 + s2 + s3;
    }
    __syncthreads();
    if (i < N_NODES) rowptr[i] = sc - v + wsum[w];   // block-local exclusive
}

// ---------------- K2b.2: exclusive scan of the 196 block sums --------------
__global__ __launch_bounds__(256) void k_scan2(int* __restrict__ bsum) {
    __shared__ int wsum[4];
    const int tid  = threadIdx.x;
    const int lane = tid & 63, w = tid >> 6;
    int v = (tid < SCAN_BLOCKS) ? bsum[tid] : 0;
    int sc = v;
    #pragma unroll
    for (int off = 1; off < 64; off <<= 1) {
        int t = __shfl_up(sc, off);
        if (lane >= off) sc += t;
    }
    if (lane == 63) wsum[w] = sc;
    __syncthreads();
    if (tid == 0) {
        int s0 = wsum[0], s1 = wsum[1], s2 = wsum[2];
        wsum[3] = s0 + s1 + s2; wsum[2] = s0 + s1; wsum[1] = s0; wsum[0] = 0;
    }
    __syncthreads();
    if (tid < SCAN_BLOCKS) bsum[tid] = sc - v + wsum[w];
}

// ---------------- K2c: scatter (src, exp(score)) pairs into CSR order ------
// Global position = local rowptr + bsum block offset (no scan3 pass).
__global__ void k_scatter(const int* __restrict__ src, const int* __restrict__ dst,
                          const float* __restrict__ ssrc, const float* __restrict__ sdst,
                          const int* __restrict__ rowptr, const int* __restrict__ bsum,
                          int* __restrict__ cursor, uint2* __restrict__ sev) {
    int e = blockIdx.x * 256 + threadIdx.x;   // exactly 800000 threads
    int s  = src[e];
    int dv = dst[e];
    float sc = ssrc[s] + sdst[dv];
    sc = sc >= 0.f ? sc : 0.2f * sc;          // LeakyReLU(0.2)
    float ex = __expf(sc);
    int pos = rowptr[dv] + bsum[dv >> 8] + atomicAdd(&cursor[dv], 1);
    sev[pos] = make_uint2((unsigned int)s, __float_as_uint(ex));
}

// ---------------- K3: per-node gather-aggregate + fused residual+LN --------
// One wave per node; lane l handles dims 2l, 2l+1. Scores precomputed, so
// per edge: 8B broadcast load + coalesced h-row load + 1 add + 2 FMA.
__global__ __launch_bounds__(256) void k_gather(
        const int* __restrict__ rowptr, const int* __restrict__ bsum,
        const uint2* __restrict__ sev,
        const unsigned short* __restrict__ hb, const float* __restrict__ x,
        const float* __restrict__ scale, const float* __restrict__ bias,
        float* __restrict__ out) {
    int n    = blockIdx.x * 4 + (threadIdx.x >> 6);
    int lane = threadIdx.x & 63;
    int beg = rowptr[n] + bsum[n >> 8];
    int end = (n == N_NODES - 1) ? E_EDGES : rowptr[n + 1] + bsum[(n + 1) >> 8];

    float a0 = 0.f, a1 = 0.f, b0 = 0.f, b1 = 0.f, den = 0.f;

    int i = beg;
    for (; i + 3 < end; i += 4) {             // 4-edge unroll: 4 h-loads in flight
        uint2 p0 = sev[i],     p1 = sev[i + 1];
        uint2 p2 = sev[i + 2], p3 = sev[i + 3];
        unsigned int u0 = *(const unsigned int*)&hb[(size_t)p0.x * 128 + 2 * lane];
        unsigned int u1 = *(const unsigned int*)&hb[(size_t)p1.x * 128 + 2 * lane];
        unsigned int u2 = *(const unsigned int*)&hb[(size_t)p2.x * 128 + 2 * lane];
        unsigned int u3 = *(const unsigned int*)&hb[(size_t)p3.x * 128 + 2 * lane];
        float ex0 = __uint_as_float(p0.y), ex1 = __uint_as_float(p1.y);
        float ex2 = __uint_as_float(p2.y), ex3 = __uint_as_float(p3.y);
        den += (ex0 + ex1) + (ex2 + ex3);
        a0 += ex0 * __uint_as_float(u0 << 16);
        a1 += ex0 * __uint_as_float(u0 & 0xFFFF0000u);
        b0 += ex1 * __uint_as_float(u1 << 16);
        b1 += ex1 * __uint_as_float(u1 & 0xFFFF0000u);
        a0 += ex2 * __uint_as_float(u2 << 16);
        a1 += ex2 * __uint_as_float(u2 & 0xFFFF0000u);
        b0 += ex3 * __uint_as_float(u3 << 16);
        b1 += ex3 * __uint_as_float(u3 & 0xFFFF0000u);
    }
    for (; i < end; ++i) {
        uint2 p0 = sev[i];
        unsigned int u0 = *(const unsigned int*)&hb[(size_t)p0.x * 128 + 2 * lane];
        float ex0 = __uint_as_float(p0.y);
        den += ex0;
        a0 += ex0 * __uint_as_float(u0 << 16);
        a1 += ex0 * __uint_as_float(u0 & 0xFFFF0000u);
    }
    a0 += b0; a1 += b1;

    float inv_d = 1.f / (den > 0.f ? den : 1.f);
    size_t base = (size_t)n * 128 + 2 * lane;
    float2 xv = *(const float2*)&x[base];
    float r0 = a0 * inv_d + xv.x;
    float r1 = a1 * inv_d + xv.y;

    float sum = r0 + r1;
    #pragma unroll
    for (int off = 32; off >= 1; off >>= 1) sum += __shfl_xor(sum, off);
    float mu = sum * (1.f / 128.f);
    float d0 = r0 - mu, d1 = r1 - mu;
    float ss = d0 * d0 + d1 * d1;
    #pragma unroll
    for (int off = 32; off >= 1; off >>= 1) ss += __shfl_xor(ss, off);
    float inv = rsqrtf(ss * (1.f / 128.f) + LN_EPS);
    float o0 = d0 * inv * scale[2 * lane]     + bias[2 * lane];
    float o1 = d1 * inv * scale[2 * lane + 1] + bias[2 * lane + 1];
    *(float2*)&out[base] = make_float2(o0, o1);
}

extern "C" void kernel_launch(void* const* d_in, const int* in_sizes, int n_in,
                              void* d_out, int out_size, void* d_ws, size_t ws_size,
                              hipStream_t stream) {
    const float* x        = (const float*)d_in[0];
    const float* W_lin    = (const float*)d_in[1];
    const float* W_attn   = (const float*)d_in[2];
    const float* ln_scale = (const float*)d_in[3];
    const float* ln_bias  = (const float*)d_in[4];
    const int*   edge     = (const int*)d_in[5];
    const int*   e_src    = edge;
    const int*   e_dst    = edge + E_EDGES;
    float* out = (float*)d_out;

    char* ws = (char*)d_ws;
    unsigned short* hb = (unsigned short*)(ws);   // 12,800,000 B
    float* Wt     = (float*)(ws + 12800000);      //     65,536 B
    float* ssrc   = (float*)(ws + 12865536);      //    200,000 B
    float* sdst   = (float*)(ws + 13065536);      //    200,000 B
    int*   count  = (int*)  (ws + 13265536);      //    200,000 B (degrees)
    int*   cursor = (int*)  (ws + 13465536);      //    200,000 B (scatter cursor)
    int*   rowptr = (int*)  (ws + 13665536);      //    200,016 B (padded)
    int*   bsum   = (int*)  (ws + 13865552);      //        800 B (padded)
    uint2* sev    = (uint2*)(ws + 13866352);      //  6,400,000 B  (~20.3 MB)

    k_prep     <<<SCAN_BLOCKS, 256, 0, stream>>>(W_lin, Wt, count, cursor);
    k_gemm_hist<<<HIST_BLOCKS + GEMM_BLOCKS, 256, 0, stream>>>(
                    x, Wt, W_attn, e_dst, count, hb, ssrc, sdst);
    k_scan1    <<<SCAN_BLOCKS, 256, 0, stream>>>(count, rowptr, bsum);
    k_scan2    <<<1,    256, 0, stream>>>(bsum);
    k_scatter  <<<HIST_BLOCKS, 256, 0, stream>>>(e_src, e_dst, ssrc, sdst,
                                                 rowptr, bsum, cursor, sev);
    k_gather   <<<12500, 256, 0, stream>>>(rowptr, bsum, sev, hb, x,
                                           ln_scale, ln_bias, out);
}

// Round 7
// 221.838 us; speedup vs baseline: 3.7500x; 1.0583x over previous
//
#include <hip/hip_runtime.h>

#define N_NODES 50000
#define E_EDGES 800000
#define D_DIM   128
#define LN_EPS  1e-5f
#define SCAN_BLOCKS 196   // ceil(50000/256)
#define HIST_BLOCKS 3125  // 800000/256 exactly
#define GEMM_BLOCKS 1563  // ceil(50000/32)

// fp32 -> bf16 (round to nearest even), stored as raw ushort
__device__ inline unsigned short f2b(float f) {
    unsigned int u = __float_as_uint(f);
    unsigned int r = u + 0x7FFFu + ((u >> 16) & 1u);
    return (unsigned short)(r >> 16);
}

// ---------------- K_prep: zero count, transpose W_lin ----------------------
__global__ void k_prep(const float* __restrict__ W, float* __restrict__ Wt,
                       int* __restrict__ count) {
    int i = blockIdx.x * 256 + threadIdx.x;
    if (i < N_NODES) count[i] = 0;
    if (i < 16384) {                          // Wt[d][o] = W[o][d]
        int d = i >> 7, o = i & 127;
        Wt[i] = W[o * 128 + d];
    }
}

// ---------------- K1: fused [gemm blocks] + [hist blocks] ------------------
// GEMM blocks FIRST (long pole starts immediately); hist blocks trail and
// fill freed slots under the GEMM. 32 KB LDS -> 5 blocks/CU (20 waves),
// matching the 88-VGPR / 5-waves-per-SIMD limit.
__global__ __launch_bounds__(256, 5) void k_gemm_hist(
        const float* __restrict__ x, const float* __restrict__ Wt,
        const float* __restrict__ Wa, const int* __restrict__ dst,
        int* __restrict__ count, unsigned short* __restrict__ hb,
        float* __restrict__ ssrc, float* __restrict__ sdst) {
    __shared__ float xl[32 * 128];   // 16 KB: 32 x-rows
    __shared__ float wl[32 * 128];   // 16 KB: one 32-deep W chunk
    const int tid = threadIdx.x;

    if (blockIdx.x >= GEMM_BLOCKS) {
        int e = (blockIdx.x - GEMM_BLOCKS) * 256 + tid;  // exactly 800000
        atomicAdd(&count[dst[e]], 1);
        return;
    }

    const int n0 = blockIdx.x * 32;

    #pragma unroll
    for (int i = 0; i < 4; ++i) {
        int idx = i * 256 + tid;
        int row = idx >> 5, d4 = idx & 31;
        int n = n0 + row; if (n >= N_NODES) n = N_NODES - 1;
        ((float4*)xl)[idx] = ((const float4*)(x + (size_t)n * 128))[d4];
    }

    const int c = tid & 31;
    const int r = tid >> 5;
    float4 acc[4];
    #pragma unroll
    for (int j = 0; j < 4; ++j) acc[j] = make_float4(0.f, 0.f, 0.f, 0.f);

    for (int p = 0; p < 4; ++p) {            // four 32-deep K chunks
        __syncthreads();                     // WAR (covers xl RAW at p=0)
        #pragma unroll
        for (int i = 0; i < 4; ++i) {
            int idx = i * 256 + tid;         // 1024 float4 = 32x128 fp32
            ((float4*)wl)[idx] = ((const float4*)(Wt + (size_t)p * 32 * 128))[idx];
        }
        __syncthreads();                     // RAW
        #pragma unroll
        for (int d4 = 0; d4 < 8; ++d4) {
            float4 xv[4];
            #pragma unroll
            for (int j = 0; j < 4; ++j)
                xv[j] = *(const float4*)&xl[(4 * r + j) * 128 + p * 32 + 4 * d4];
            #pragma unroll
            for (int k = 0; k < 4; ++k) {
                float4 wv = *(const float4*)&wl[(4 * d4 + k) * 128 + 4 * c];
                #pragma unroll
                for (int j = 0; j < 4; ++j) {
                    float xs = (&xv[j].x)[k];
                    acc[j].x += xs * wv.x; acc[j].y += xs * wv.y;
                    acc[j].z += xs * wv.z; acc[j].w += xs * wv.w;
                }
            }
        }
    }

    float as0 = Wa[4*c],     as1 = Wa[4*c+1],     as2 = Wa[4*c+2],     as3 = Wa[4*c+3];
    float ad0 = Wa[128+4*c], ad1 = Wa[128+4*c+1], ad2 = Wa[128+4*c+2], ad3 = Wa[128+4*c+3];
    #pragma unroll
    for (int j = 0; j < 4; ++j) {
        int n = n0 + 4 * r + j;
        float ps = acc[j].x*as0 + acc[j].y*as1 + acc[j].z*as2 + acc[j].w*as3;
        float pd = acc[j].x*ad0 + acc[j].y*ad1 + acc[j].z*ad2 + acc[j].w*ad3;
        #pragma unroll
        for (int off = 16; off >= 1; off >>= 1) {
            ps += __shfl_xor(ps, off);
            pd += __shfl_xor(pd, off);
        }
        if (n < N_NODES) {
            ushort4 b4;
            b4.x = f2b(acc[j].x); b4.y = f2b(acc[j].y);
            b4.z = f2b(acc[j].z); b4.w = f2b(acc[j].w);
            *(ushort4*)&hb[(size_t)n * 128 + 4 * c] = b4;
            if (c == 0) { ssrc[n] = ps; sdst[n] = pd; }
        }
    }
}

// ---------------- K2b.1: per-block exclusive scan (256 elems/block) --------
__global__ __launch_bounds__(256) void k_scan1(const int* __restrict__ count,
                                               int* __restrict__ rowptr,
                                               int* __restrict__ bsum) {
    __shared__ int wsum[4];
    const int tid  = threadIdx.x;
    const int lane = tid & 63, w = tid >> 6;
    int i = blockIdx.x * 256 + tid;
    int v = (i < N_NODES) ? count[i] : 0;
    int sc = v;
    #pragma unroll
    for (int off = 1; off < 64; off <<= 1) {
        int t = __shfl_up(sc, off);
        if (lane >= off) sc += t;
    }
    if (lane == 63) wsum[w] = sc;
    __syncthreads();
    if (tid == 0) {
        int s0 = wsum[0], s1 = wsum[1], s2 = wsum[2], s3 = wsum[3];
        wsum[0] = 0; wsum[1] = s0; wsum[2] = s0 + s1; wsum[3] = s0 + s1 + s2;
        bsum[blockIdx.x] = s0 + s1 + s2 + s3;
    }
    __syncthreads();
    if (i < N_NODES) rowptr[i] = sc - v + wsum[w];   // block-local exclusive
}

// ---------------- K2b.2: exclusive scan of the 196 block sums --------------
__global__ __launch_bounds__(256) void k_scan2(int* __restrict__ bsum) {
    __shared__ int wsum[4];
    const int tid  = threadIdx.x;
    const int lane = tid & 63, w = tid >> 6;
    int v = (tid < SCAN_BLOCKS) ? bsum[tid] : 0;
    int sc = v;
    #pragma unroll
    for (int off = 1; off < 64; off <<= 1) {
        int t = __shfl_up(sc, off);
        if (lane >= off) sc += t;
    }
    if (lane == 63) wsum[w] = sc;
    __syncthreads();
    if (tid == 0) {
        int s0 = wsum[0], s1 = wsum[1], s2 = wsum[2];
        wsum[3] = s0 + s1 + s2; wsum[2] = s0 + s1; wsum[1] = s0; wsum[0] = 0;
    }
    __syncthreads();
    if (tid < SCAN_BLOCKS) bsum[tid] = sc - v + wsum[w];
}

// ---------------- K2c: scatter (src, exp(score)) pairs into CSR order ------
// count (degrees, already consumed by scan1) doubles as the cursor via
// atomicSub -> positions fill end-1..0 within each segment (order-free sum).
__global__ void k_scatter(const int* __restrict__ src, const int* __restrict__ dst,
                          const float* __restrict__ ssrc, const float* __restrict__ sdst,
                          const int* __restrict__ rowptr, const int* __restrict__ bsum,
                          int* __restrict__ count, uint2* __restrict__ sev) {
    int e = blockIdx.x * 256 + threadIdx.x;   // exactly 800000 threads
    int s  = src[e];
    int dv = dst[e];
    float sc = ssrc[s] + sdst[dv];
    sc = sc >= 0.f ? sc : 0.2f * sc;          // LeakyReLU(0.2)
    float ex = __expf(sc);
    int pos = rowptr[dv] + bsum[dv >> 8] + (atomicSub(&count[dv], 1) - 1);
    sev[pos] = make_uint2((unsigned int)s, __float_as_uint(ex));
}

// ---------------- K3: per-node gather-aggregate + fused residual+LN --------
// One wave per node; lane l handles dims 2l, 2l+1. Scores precomputed, so
// per edge: 8B broadcast load + coalesced h-row load + 1 add + 2 FMA.
__global__ __launch_bounds__(256) void k_gather(
        const int* __restrict__ rowptr, const int* __restrict__ bsum,
        const uint2* __restrict__ sev,
        const unsigned short* __restrict__ hb, const float* __restrict__ x,
        const float* __restrict__ scale, const float* __restrict__ bias,
        float* __restrict__ out) {
    int n    = blockIdx.x * 4 + (threadIdx.x >> 6);
    int lane = threadIdx.x & 63;
    int beg = rowptr[n] + bsum[n >> 8];
    int end = (n == N_NODES - 1) ? E_EDGES : rowptr[n + 1] + bsum[(n + 1) >> 8];

    float a0 = 0.f, a1 = 0.f, b0 = 0.f, b1 = 0.f, den = 0.f;

    int i = beg;
    for (; i + 3 < end; i += 4) {             // 4-edge unroll: 4 h-loads in flight
        uint2 p0 = sev[i],     p1 = sev[i + 1];
        uint2 p2 = sev[i + 2], p3 = sev[i + 3];
        unsigned int u0 = *(const unsigned int*)&hb[(size_t)p0.x * 128 + 2 * lane];
        unsigned int u1 = *(const unsigned int*)&hb[(size_t)p1.x * 128 + 2 * lane];
        unsigned int u2 = *(const unsigned int*)&hb[(size_t)p2.x * 128 + 2 * lane];
        unsigned int u3 = *(const unsigned int*)&hb[(size_t)p3.x * 128 + 2 * lane];
        float ex0 = __uint_as_float(p0.y), ex1 = __uint_as_float(p1.y);
        float ex2 = __uint_as_float(p2.y), ex3 = __uint_as_float(p3.y);
        den += (ex0 + ex1) + (ex2 + ex3);
        a0 += ex0 * __uint_as_float(u0 << 16);
        a1 += ex0 * __uint_as_float(u0 & 0xFFFF0000u);
        b0 += ex1 * __uint_as_float(u1 << 16);
        b1 += ex1 * __uint_as_float(u1 & 0xFFFF0000u);
        a0 += ex2 * __uint_as_float(u2 << 16);
        a1 += ex2 * __uint_as_float(u2 & 0xFFFF0000u);
        b0 += ex3 * __uint_as_float(u3 << 16);
        b1 += ex3 * __uint_as_float(u3 & 0xFFFF0000u);
    }
    for (; i < end; ++i) {
        uint2 p0 = sev[i];
        unsigned int u0 = *(const unsigned int*)&hb[(size_t)p0.x * 128 + 2 * lane];
        float ex0 = __uint_as_float(p0.y);
        den += ex0;
        a0 += ex0 * __uint_as_float(u0 << 16);
        a1 += ex0 * __uint_as_float(u0 & 0xFFFF0000u);
    }
    a0 += b0; a1 += b1;

    float inv_d = 1.f / (den > 0.f ? den : 1.f);
    size_t base = (size_t)n * 128 + 2 * lane;
    float2 xv = *(const float2*)&x[base];
    float r0 = a0 * inv_d + xv.x;
    float r1 = a1 * inv_d + xv.y;

    float sum = r0 + r1;
    #pragma unroll
    for (int off = 32; off >= 1; off >>= 1) sum += __shfl_xor(sum, off);
    float mu = sum * (1.f / 128.f);
    float d0 = r0 - mu, d1 = r1 - mu;
    float ss = d0 * d0 + d1 * d1;
    #pragma unroll
    for (int off = 32; off >= 1; off >>= 1) ss += __shfl_xor(ss, off);
    float inv = rsqrtf(ss * (1.f / 128.f) + LN_EPS);
    float o0 = d0 * inv * scale[2 * lane]     + bias[2 * lane];
    float o1 = d1 * inv * scale[2 * lane + 1] + bias[2 * lane + 1];
    *(float2*)&out[base] = make_float2(o0, o1);
}

extern "C" void kernel_launch(void* const* d_in, const int* in_sizes, int n_in,
                              void* d_out, int out_size, void* d_ws, size_t ws_size,
                              hipStream_t stream) {
    const float* x        = (const float*)d_in[0];
    const float* W_lin    = (const float*)d_in[1];
    const float* W_attn   = (const float*)d_in[2];
    const float* ln_scale = (const float*)d_in[3];
    const float* ln_bias  = (const float*)d_in[4];
    const int*   edge     = (const int*)d_in[5];
    const int*   e_src    = edge;
    const int*   e_dst    = edge + E_EDGES;
    float* out = (float*)d_out;

    char* ws = (char*)d_ws;
    unsigned short* hb = (unsigned short*)(ws);   // 12,800,000 B
    float* Wt     = (float*)(ws + 12800000);      //     65,536 B
    float* ssrc   = (float*)(ws + 12865536);      //    200,000 B
    float* sdst   = (float*)(ws + 13065536);      //    200,000 B
    int*   count  = (int*)  (ws + 13265536);      //    200,000 B (degrees, then cursor)
    int*   rowptr = (int*)  (ws + 13465536);      //    200,016 B (padded)
    int*   bsum   = (int*)  (ws + 13665552);      //        800 B (padded)
    uint2* sev    = (uint2*)(ws + 13666352);      //  6,400,000 B  (~20.1 MB)

    k_prep     <<<SCAN_BLOCKS, 256, 0, stream>>>(W_lin, Wt, count);
    k_gemm_hist<<<GEMM_BLOCKS + HIST_BLOCKS, 256, 0, stream>>>(
                    x, Wt, W_attn, e_dst, count, hb, ssrc, sdst);
    k_scan1    <<<SCAN_BLOCKS, 256, 0, stream>>>(count, rowptr, bsum);
    k_scan2    <<<1,    256, 0, stream>>>(bsum);
    k_scatter  <<<HIST_BLOCKS, 256, 0, stream>>>(e_src, e_dst, ssrc, sdst,
                                                 rowptr, bsum, count, sev);
    k_gather   <<<12500, 256, 0, stream>>>(rowptr, bsum, sev, hb, x,
                                           ln_scale, ln_bias, out);
}